// Round 4
// baseline (7524.607 us; speedup 1.0000x reference)
//
#include <hip/hip_runtime.h>
#include <hip/hip_bf16.h>
#include <cstdint>
#include <cstddef>

#define B_ 32
#define T_ 128
#define H_ 1024
#define V_ 32000
#define NBREC 64           // rec_layer blocks: 64 x 16 units

using bf16 = __hip_bfloat16;
typedef __attribute__((ext_vector_type(8))) short short8;
typedef __attribute__((ext_vector_type(4))) float f32x4;

__device__ __forceinline__ float bf2f(unsigned short u) {
    return __uint_as_float(((unsigned)u) << 16);
}

__device__ __forceinline__ void lds_cp16(const void* g, void* l) {
    __builtin_amdgcn_global_load_lds(
        (const __attribute__((address_space(1))) unsigned int*)g,
        (__attribute__((address_space(3))) unsigned int*)l, 16, 0, 0);
}

// ---------------------------------------------------------------------------
// f32 -> bf16 conversion, 8 elements/thread
__global__ __launch_bounds__(256)
void conv_kernel(const float* __restrict__ src, bf16* __restrict__ dst, int n8) {
    int i = blockIdx.x * 256 + threadIdx.x;
    if (i >= n8) return;
    const float4* s = (const float4*)(src + (size_t)i * 8);
    float4 a = s[0], b = s[1];
    ushort4 o0, o1;
    o0.x = __bfloat16_as_ushort(__float2bfloat16(a.x));
    o0.y = __bfloat16_as_ushort(__float2bfloat16(a.y));
    o0.z = __bfloat16_as_ushort(__float2bfloat16(a.z));
    o0.w = __bfloat16_as_ushort(__float2bfloat16(a.w));
    o1.x = __bfloat16_as_ushort(__float2bfloat16(b.x));
    o1.y = __bfloat16_as_ushort(__float2bfloat16(b.y));
    o1.z = __bfloat16_as_ushort(__float2bfloat16(b.z));
    o1.w = __bfloat16_as_ushort(__float2bfloat16(b.w));
    ((ushort4*)(dst + (size_t)i * 8))[0] = o0;
    ((ushort4*)(dst + (size_t)i * 8))[1] = o1;
}

// ---------------------------------------------------------------------------
// embed: X[t*B+b] = [bf16(word_emb[token]) | bf16(cat_emb[cat])]
__global__ __launch_bounds__(256)
void embed_kernel(const int* __restrict__ tok, const int* __restrict__ cat,
                  const float* __restrict__ wemb, const float* __restrict__ cemb,
                  bf16* __restrict__ X) {
    const int tb = blockIdx.x;
    const int t = tb >> 5, b = tb & 31;
    const int token = tok[b * T_ + t];
    const int c = cat[b * T_ + t];
    const int i = threadIdx.x;
    const float* src = (i < 128) ? (wemb + (size_t)token * H_ + (size_t)i * 8)
                                 : (cemb + (size_t)c * H_ + (size_t)(i - 128) * 8);
    float4 a = ((const float4*)src)[0];
    float4 bv = ((const float4*)src)[1];
    ushort4 o0, o1;
    o0.x = __bfloat16_as_ushort(__float2bfloat16(a.x));
    o0.y = __bfloat16_as_ushort(__float2bfloat16(a.y));
    o0.z = __bfloat16_as_ushort(__float2bfloat16(a.z));
    o0.w = __bfloat16_as_ushort(__float2bfloat16(a.w));
    o1.x = __bfloat16_as_ushort(__float2bfloat16(bv.x));
    o1.y = __bfloat16_as_ushort(__float2bfloat16(bv.y));
    o1.z = __bfloat16_as_ushort(__float2bfloat16(bv.z));
    o1.w = __bfloat16_as_ushort(__float2bfloat16(bv.w));
    ushort4* d = (ushort4*)(X + (size_t)tb * 2 * H_ + (size_t)i * 8);
    d[0] = o0;
    d[1] = o1;
}

// ---------------------------------------------------------------------------
// MFMA GEMM: C[M,N] = A[M,K] @ Bm[N,K]^T + bias[N]   (A,Bm bf16; bias f32)
// MODE 0: Cf fp32 row-major; MODE 1: scattered (b*T+t) rows
template<int MODE>
__global__ __launch_bounds__(256)
void gemm_bt(const bf16* __restrict__ A, const bf16* __restrict__ Bm,
             const float* __restrict__ bias, float* __restrict__ Cf,
             int M, int N, int K) {
    __shared__ __align__(16) bf16 As[128 * 64];
    __shared__ __align__(16) bf16 Bs[128 * 64];
    const int tid = threadIdx.x;
    const int lane = tid & 63;
    const int wid = tid >> 6;
    const int row0 = blockIdx.x * 128;
    const int col0 = blockIdx.y * 128;
    const int rw0 = (wid >> 1) * 64;
    const int cw0 = (wid & 1) * 64;
    const int lr = lane & 15;
    const int lg = lane >> 4;
    f32x4 acc[4][4] = {};
    const int nk = K >> 6;
    for (int kt = 0; kt < nk; ++kt) {
        const int k0 = kt * 64;
#pragma unroll
        for (int i = 0; i < 4; ++i) {
            int c = i * 256 + tid;
            int r = c >> 3;
            int kc = (c & 7) * 8;
            lds_cp16(A + (size_t)(row0 + r) * K + (k0 + kc), (void*)(As + c * 8));
            lds_cp16(Bm + (size_t)(col0 + r) * K + (k0 + kc), (void*)(Bs + c * 8));
        }
        __syncthreads();
#pragma unroll
        for (int s = 0; s < 2; ++s) {
            short8 af[4], bfr[4];
#pragma unroll
            for (int m = 0; m < 4; ++m)
                af[m] = *(const short8*)(As + (rw0 + m * 16 + lr) * 64 + s * 32 + lg * 8);
#pragma unroll
            for (int n = 0; n < 4; ++n)
                bfr[n] = *(const short8*)(Bs + (cw0 + n * 16 + lr) * 64 + s * 32 + lg * 8);
#pragma unroll
            for (int m = 0; m < 4; ++m)
#pragma unroll
                for (int n = 0; n < 4; ++n)
                    acc[m][n] = __builtin_amdgcn_mfma_f32_16x16x32_bf16(af[m], bfr[n], acc[m][n], 0, 0, 0);
        }
        __syncthreads();
    }
#pragma unroll
    for (int m = 0; m < 4; ++m) {
#pragma unroll
        for (int n = 0; n < 4; ++n) {
#pragma unroll
            for (int i = 0; i < 4; ++i) {
                int r = row0 + rw0 + m * 16 + lg * 4 + i;
                int cc = col0 + cw0 + n * 16 + lr;
                float v = acc[m][n][i] + bias[cc];
                if (MODE == 0) {
                    Cf[(size_t)r * N + cc] = v;
                } else {
                    int b = r & 31, t = r >> 5;
                    Cf[((size_t)b * T_ + t) * (size_t)N + cc] = v;
                }
            }
        }
    }
}

// ---------------------------------------------------------------------------
// hbinit: bf16 snapshot of initial h into Hb[0], zero barrier slot
__global__ __launch_bounds__(256)
void hbinit_kernel(const float* __restrict__ h, bf16* __restrict__ Hb,
                   int* __restrict__ bar) {
    int i = blockIdx.x * 256 + threadIdx.x;   // < 32768
    Hb[i] = __float2bfloat16(h[i]);
    if (i == 0) { bar[0] = 0; bar[1] = 0; }
}

// ---------------------------------------------------------------------------
// device-scope sense barrier (monotonic count; NBREC blocks, co-resident)
__device__ __forceinline__ void grid_barrier(int* bar, int step) {
    __threadfence();               // flush my global stores agent-wide
    __syncthreads();
    if (threadIdx.x == 0) {
        int v = __hip_atomic_fetch_add(&bar[0], 1, __ATOMIC_ACQ_REL, __HIP_MEMORY_SCOPE_AGENT);
        if (v == (step + 1) * NBREC - 1) {
            __hip_atomic_store(&bar[1], step + 1, __ATOMIC_RELEASE, __HIP_MEMORY_SCOPE_AGENT);
        } else {
            while (__hip_atomic_load(&bar[1], __ATOMIC_ACQUIRE, __HIP_MEMORY_SCOPE_AGENT) < step + 1)
                __builtin_amdgcn_s_sleep(2);
        }
    }
    __syncthreads();
    __threadfence();               // invalidate caches before reading others' h
}

// ---------------------------------------------------------------------------
// Persistent per-layer recurrence. 64 blocks x 256 thr (4 waves).
// Block owns 16 hidden units (u0..u0+15). Wave wid owns K-slice [wid*256, +256).
// Whh fragments live in VGPRs for the whole layer (3 gates x 8 kfrags x short8).
// Per step: MFMA gh partials -> LDS (K-swizzled) -> ks-reduce -> gates -> publish.
__global__ __launch_bounds__(256)
void rec_layer(const float* __restrict__ GI, const bf16* __restrict__ WhhB,
               const float* __restrict__ bhh, const float* __restrict__ hinit,
               bf16* __restrict__ Hb, bf16* __restrict__ Cout,
               float* __restrict__ htail, int* __restrict__ bar) {
    __shared__ float Pl[4 * 1536];   // [ks][col(48)][b(32)] f32, swizzled  (24KB)
    __shared__ float Rr[1536];       // [col][b] reduced                    (6KB)
    __shared__ float ho[512];        // [b][u] own h, f32                   (2KB)
    const int tid = threadIdx.x;
    const int lane = tid & 63;
    const int wid = tid >> 6;        // K-slice
    const int lr = lane & 15;
    const int lg = lane >> 4;
    const int u0 = blockIdx.x * 16;
    const int kbase = wid * 256;

    // persistent weight fragments: rows g*1024 + u0 + lr, k = kbase + kf*32 + lg*8
    short8 wf[3][8];
#pragma unroll
    for (int g = 0; g < 3; ++g)
#pragma unroll
        for (int kf = 0; kf < 8; ++kf)
            wf[g][kf] = *(const short8*)((const unsigned short*)WhhB +
                          (size_t)(g * 1024 + u0 + lr) * 1024 + kbase + kf * 32 + lg * 8);

    // own h (f32) init: p -> (b = p>>4, u = p&15)
#pragma unroll
    for (int it = 0; it < 2; ++it) {
        int p = tid + it * 256;
        int b = p >> 4, u = p & 15;
        ho[p] = hinit[(size_t)b * H_ + u0 + u];
    }
    // hoist bhh for reduce tasks (2 per thread; task = tid + it*256 < 384)
    float bh0 = 0.f, bh1 = 0.f;
    {
        int task = tid;
        int col = task >> 3;
        bh0 = bhh[(col >> 4) * 1024 + u0 + (col & 15)];
        if (tid < 128) {
            int col1 = (tid + 256) >> 3;
            bh1 = bhh[(col1 >> 4) * 1024 + u0 + (col1 & 15)];
        }
    }
    __syncthreads();

    for (int t = 0; t < T_; ++t) {
        const unsigned short* src = (const unsigned short*)(Hb + (t & 1) * (B_ * H_));
        // --- MFMA: gh partial for this K-slice ---
        f32x4 acc[2][3] = {};
#pragma unroll
        for (int kf = 0; kf < 8; ++kf) {
            short8 a0 = *(const short8*)(src + (size_t)(lr) * 1024 + kbase + kf * 32 + lg * 8);
            short8 a1 = *(const short8*)(src + (size_t)(16 + lr) * 1024 + kbase + kf * 32 + lg * 8);
#pragma unroll
            for (int g = 0; g < 3; ++g) {
                acc[0][g] = __builtin_amdgcn_mfma_f32_16x16x32_bf16(a0, wf[g][kf], acc[0][g], 0, 0, 0);
                acc[1][g] = __builtin_amdgcn_mfma_f32_16x16x32_bf16(a1, wf[g][kf], acc[1][g], 0, 0, 0);
            }
        }
        // --- psum -> LDS (swizzled): col = g*16+lr, batch-quad b4 = m*16+lg*4 ---
#pragma unroll
        for (int m = 0; m < 2; ++m)
#pragma unroll
            for (int g = 0; g < 3; ++g) {
                int col = g * 16 + lr;
                int key = (col + (col >> 3)) & 7;
                int byte_off = wid * 6144 + col * 128 + (((m * 16 + lg * 4) * 4) ^ (key << 4));
                *(f32x4*)((char*)Pl + byte_off) = acc[m][g];
            }
        __syncthreads();
        // --- ks-reduce + bias -> Rr ---
#pragma unroll
        for (int it = 0; it < 2; ++it) {
            int task = tid + it * 256;
            if (task < 384) {
                int col = task >> 3, bq = task & 7;
                int key = (col + (col >> 3)) & 7;
                int boff = col * 128 + ((bq * 16) ^ (key << 4));
                f32x4 s0 = *(const f32x4*)((const char*)Pl + boff);
                f32x4 s1 = *(const f32x4*)((const char*)Pl + 6144 + boff);
                f32x4 s2 = *(const f32x4*)((const char*)Pl + 12288 + boff);
                f32x4 s3 = *(const f32x4*)((const char*)Pl + 18432 + boff);
                f32x4 s = (s0 + s1) + (s2 + s3);
                float bh = (it == 0) ? bh0 : bh1;
                s[0] += bh; s[1] += bh; s[2] += bh; s[3] += bh;
                *(f32x4*)((char*)Rr + boff) = s;
            }
        }
        __syncthreads();
        // --- gates: p -> (b = p>>4, u = p&15) ---
        bf16* dst = Hb + ((t + 1) & 1) * (B_ * H_);
#pragma unroll
        for (int it = 0; it < 2; ++it) {
            int p = tid + it * 256;
            int b = p >> 4, u = p & 15;
            int keyr = (u + (u >> 3)) & 7;           // cols u,16+u,32+u share (col&7)=u&7... key uses col>>3 too
            int colR = u, colZ = 16 + u, colN = 32 + u;
            int keyZ = (colZ + (colZ >> 3)) & 7;
            int keyN = (colN + (colN >> 3)) & 7;
            float gr = *(const float*)((const char*)Rr + colR * 128 + ((b * 4) ^ (keyr << 4)));
            float gz = *(const float*)((const char*)Rr + colZ * 128 + ((b * 4) ^ (keyZ << 4)));
            float gn = *(const float*)((const char*)Rr + colN * 128 + ((b * 4) ^ (keyN << 4)));
            const float* gi = GI + ((size_t)t * B_ + b) * 3072 + u0 + u;
            float hold = ho[p];
            float rr = 1.f / (1.f + expf(-(gi[0] + gr)));
            float zz = 1.f / (1.f + expf(-(gi[1024] + gz)));
            float nn = tanhf(gi[2048] + rr * gn);
            float hnew = (1.f - zz) * nn + zz * hold;
            ho[p] = hnew;
            unsigned short hb = __bfloat16_as_ushort(__float2bfloat16(hnew));
            ((unsigned short*)dst)[(size_t)b * H_ + u0 + u] = hb;
            ((unsigned short*)Cout)[((size_t)t * B_ + b) * H_ + u0 + u] = hb;
        }
        grid_barrier(bar, t);
    }
    // final h tail (f32)
#pragma unroll
    for (int it = 0; it < 2; ++it) {
        int p = tid + it * 256;
        int b = p >> 4, u = p & 15;
        htail[(size_t)b * H_ + u0 + u] = ho[p];
    }
}

// ---------------------------------------------------------------------------
extern "C" void kernel_launch(void* const* d_in, const int* in_sizes, int n_in,
                              void* d_out, int out_size, void* d_ws, size_t ws_size,
                              hipStream_t stream) {
    const int* tok = (const int*)d_in[0];
    const int* cat = (const int*)d_in[1];
    const float* h1 = (const float*)d_in[3];
    const float* h2 = (const float*)d_in[4];
    const float* h3 = (const float*)d_in[5];
    const float* wemb = (const float*)d_in[6];
    const float* cemb = (const float*)d_in[7];
    const float* Wih[3] = {(const float*)d_in[8], (const float*)d_in[12], (const float*)d_in[16]};
    const float* Whh[3] = {(const float*)d_in[9], (const float*)d_in[13], (const float*)d_in[17]};
    const float* bih[3] = {(const float*)d_in[10], (const float*)d_in[14], (const float*)d_in[18]};
    const float* bhh[3] = {(const float*)d_in[11], (const float*)d_in[15], (const float*)d_in[19]};
    const float* fcw = (const float*)d_in[20];
    const float* fcb = (const float*)d_in[21];
    float* out = (float*)d_out;
    const float* hins[3] = {h1, h2, h3};

    // ws layout (bytes):
    //   C3    @ 0           8,388,608
    //   Xbf   @ 8,388,608   16,777,216 -> 25,165,824
    //   C1    @ 25,165,824   8,388,608 -> 33,554,432
    //   C2    @ 33,554,432   8,388,608 -> 41,943,040
    //   GI    @ 41,943,040  50,331,648 -> 92,274,688
    //   fcwB  @ 8,388,608   65,536,000 -> 73,924,608 (reclaims Xbf/C1/C2 post-rec3)
    //   WihB1 @ 92,274,688  12,582,912 -> 104,857,600
    //   WihB2 @104,857,600   6,291,456 -> 111,149,056
    //   WihB3 @111,149,056   6,291,456 -> 117,440,512
    //   WhhB1 @117,440,512   6,291,456 -> 123,731,968
    //   WhhB2 @123,731,968   6,291,456 -> 130,023,424
    //   WhhB3 @130,023,424   6,291,456 -> 136,314,880
    //   Hb    @136,314,880     131,072 -> 136,445,952  (2 x 32x1024 bf16)
    //   bar   @136,445,952         256 -> 136,446,208
    char* ws = (char*)d_ws;
    bf16* C3 = (bf16*)ws;
    bf16* Xbf = (bf16*)(ws + 8388608);
    bf16* C1 = (bf16*)(ws + 25165824);
    bf16* C2 = (bf16*)(ws + 33554432);
    float* GI = (float*)(ws + 41943040);
    bf16* fcwB = (bf16*)(ws + 8388608);
    bf16* WihB[3] = {(bf16*)(ws + 92274688), (bf16*)(ws + 104857600), (bf16*)(ws + 111149056)};
    bf16* WhhB[3] = {(bf16*)(ws + 117440512), (bf16*)(ws + 123731968), (bf16*)(ws + 130023424)};
    bf16* Hb = (bf16*)(ws + 136314880);
    int* bar = (int*)(ws + 136445952);
    bf16* Cs[3] = {C1, C2, C3};

    conv_kernel<<<3072, 256, 0, stream>>>(Wih[0], WihB[0], 786432);
    conv_kernel<<<1536, 256, 0, stream>>>(Wih[1], WihB[1], 393216);
    conv_kernel<<<1536, 256, 0, stream>>>(Wih[2], WihB[2], 393216);
    conv_kernel<<<1536, 256, 0, stream>>>(Whh[0], WhhB[0], 393216);
    conv_kernel<<<1536, 256, 0, stream>>>(Whh[1], WhhB[1], 393216);
    conv_kernel<<<1536, 256, 0, stream>>>(Whh[2], WhhB[2], 393216);
    embed_kernel<<<T_ * B_, 256, 0, stream>>>(tok, cat, wemb, cemb, Xbf);

    for (int layer = 0; layer < 3; ++layer) {
        const bf16* Ain = (layer == 0) ? Xbf : Cs[layer - 1];
        int K = (layer == 0) ? 2048 : 1024;
        gemm_bt<0><<<dim3(32, 24), 256, 0, stream>>>(Ain, WihB[layer], bih[layer],
                                                     GI, 4096, 3072, K);
        hbinit_kernel<<<128, 256, 0, stream>>>(hins[layer], Hb, bar);
        rec_layer<<<NBREC, 256, 0, stream>>>(GI, WhhB[layer], bhh[layer], hins[layer],
                                             Hb, Cs[layer],
                                             out + (size_t)B_ * T_ * V_ + (size_t)layer * B_ * H_,
                                             bar);
    }
    conv_kernel<<<16000, 256, 0, stream>>>(fcw, fcwB, 4096000);
    gemm_bt<1><<<dim3(32, 250), 256, 0, stream>>>(C3, fcwB, fcb, out, 4096, 32000, 1024);
}

// Round 5
// 2758.829 us; speedup vs baseline: 2.7275x; 2.7275x over previous
//
#include <hip/hip_runtime.h>
#include <hip/hip_bf16.h>
#include <cstdint>
#include <cstddef>

#define B_ 32
#define T_ 128
#define H_ 1024
#define V_ 32000

using bf16 = __hip_bfloat16;
typedef __attribute__((ext_vector_type(8))) short short8;
typedef __attribute__((ext_vector_type(4))) float f32x4;

__device__ __forceinline__ float bf2f(unsigned short u) {
    return __uint_as_float(((unsigned)u) << 16);
}

__device__ __forceinline__ void lds_cp16(const void* g, void* l) {
    __builtin_amdgcn_global_load_lds(
        (const __attribute__((address_space(1))) unsigned int*)g,
        (__attribute__((address_space(3))) unsigned int*)l, 16, 0, 0);
}

// ---------------------------------------------------------------------------
// f32 -> bf16 conversion, 8 elements/thread
__global__ __launch_bounds__(256)
void conv_kernel(const float* __restrict__ src, bf16* __restrict__ dst, int n8) {
    int i = blockIdx.x * 256 + threadIdx.x;
    if (i >= n8) return;
    const float4* s = (const float4*)(src + (size_t)i * 8);
    float4 a = s[0], b = s[1];
    ushort4 o0, o1;
    o0.x = __bfloat16_as_ushort(__float2bfloat16(a.x));
    o0.y = __bfloat16_as_ushort(__float2bfloat16(a.y));
    o0.z = __bfloat16_as_ushort(__float2bfloat16(a.z));
    o0.w = __bfloat16_as_ushort(__float2bfloat16(a.w));
    o1.x = __bfloat16_as_ushort(__float2bfloat16(b.x));
    o1.y = __bfloat16_as_ushort(__float2bfloat16(b.y));
    o1.z = __bfloat16_as_ushort(__float2bfloat16(b.z));
    o1.w = __bfloat16_as_ushort(__float2bfloat16(b.w));
    ((ushort4*)(dst + (size_t)i * 8))[0] = o0;
    ((ushort4*)(dst + (size_t)i * 8))[1] = o1;
}

// ---------------------------------------------------------------------------
// embed: X[t*B+b] = [bf16(word_emb[token]) | bf16(cat_emb[cat])]
__global__ __launch_bounds__(256)
void embed_kernel(const int* __restrict__ tok, const int* __restrict__ cat,
                  const float* __restrict__ wemb, const float* __restrict__ cemb,
                  bf16* __restrict__ X) {
    const int tb = blockIdx.x;
    const int t = tb >> 5, b = tb & 31;
    const int token = tok[b * T_ + t];
    const int c = cat[b * T_ + t];
    const int i = threadIdx.x;
    const float* src = (i < 128) ? (wemb + (size_t)token * H_ + (size_t)i * 8)
                                 : (cemb + (size_t)c * H_ + (size_t)(i - 128) * 8);
    float4 a = ((const float4*)src)[0];
    float4 bv = ((const float4*)src)[1];
    ushort4 o0, o1;
    o0.x = __bfloat16_as_ushort(__float2bfloat16(a.x));
    o0.y = __bfloat16_as_ushort(__float2bfloat16(a.y));
    o0.z = __bfloat16_as_ushort(__float2bfloat16(a.z));
    o0.w = __bfloat16_as_ushort(__float2bfloat16(a.w));
    o1.x = __bfloat16_as_ushort(__float2bfloat16(bv.x));
    o1.y = __bfloat16_as_ushort(__float2bfloat16(bv.y));
    o1.z = __bfloat16_as_ushort(__float2bfloat16(bv.z));
    o1.w = __bfloat16_as_ushort(__float2bfloat16(bv.w));
    ushort4* d = (ushort4*)(X + (size_t)tb * 2 * H_ + (size_t)i * 8);
    d[0] = o0;
    d[1] = o1;
}

// ---------------------------------------------------------------------------
// MFMA GEMM: C[M,N] = A[M,K] @ Bm[N,K]^T + bias[N]   (A,Bm bf16; bias f32)
// MODE 0: Cf fp32 row-major; MODE 1: scattered (b*T+t) rows
template<int MODE>
__global__ __launch_bounds__(256)
void gemm_bt(const bf16* __restrict__ A, const bf16* __restrict__ Bm,
             const float* __restrict__ bias, float* __restrict__ Cf,
             int M, int N, int K) {
    __shared__ __align__(16) bf16 As[128 * 64];
    __shared__ __align__(16) bf16 Bs[128 * 64];
    const int tid = threadIdx.x;
    const int lane = tid & 63;
    const int wid = tid >> 6;
    const int row0 = blockIdx.x * 128;
    const int col0 = blockIdx.y * 128;
    const int rw0 = (wid >> 1) * 64;
    const int cw0 = (wid & 1) * 64;
    const int lr = lane & 15;
    const int lg = lane >> 4;
    f32x4 acc[4][4] = {};
    const int nk = K >> 6;
    for (int kt = 0; kt < nk; ++kt) {
        const int k0 = kt * 64;
#pragma unroll
        for (int i = 0; i < 4; ++i) {
            int c = i * 256 + tid;
            int r = c >> 3;
            int kc = (c & 7) * 8;
            lds_cp16(A + (size_t)(row0 + r) * K + (k0 + kc), (void*)(As + c * 8));
            lds_cp16(Bm + (size_t)(col0 + r) * K + (k0 + kc), (void*)(Bs + c * 8));
        }
        __syncthreads();
#pragma unroll
        for (int s = 0; s < 2; ++s) {
            short8 af[4], bfr[4];
#pragma unroll
            for (int m = 0; m < 4; ++m)
                af[m] = *(const short8*)(As + (rw0 + m * 16 + lr) * 64 + s * 32 + lg * 8);
#pragma unroll
            for (int n = 0; n < 4; ++n)
                bfr[n] = *(const short8*)(Bs + (cw0 + n * 16 + lr) * 64 + s * 32 + lg * 8);
#pragma unroll
            for (int m = 0; m < 4; ++m)
#pragma unroll
                for (int n = 0; n < 4; ++n)
                    acc[m][n] = __builtin_amdgcn_mfma_f32_16x16x32_bf16(af[m], bfr[n], acc[m][n], 0, 0, 0);
        }
        __syncthreads();
    }
#pragma unroll
    for (int m = 0; m < 4; ++m) {
#pragma unroll
        for (int n = 0; n < 4; ++n) {
#pragma unroll
            for (int i = 0; i < 4; ++i) {
                int r = row0 + rw0 + m * 16 + lg * 4 + i;
                int cc = col0 + cw0 + n * 16 + lr;
                float v = acc[m][n][i] + bias[cc];
                if (MODE == 0) {
                    Cf[(size_t)r * N + cc] = v;
                } else {
                    int b = r & 31, t = r >> 5;
                    Cf[((size_t)b * T_ + t) * (size_t)N + cc] = v;
                }
            }
        }
    }
}

// ---------------------------------------------------------------------------
// stair_init: Hb parity-0 = bf16(h_l), Hf = f32 h_l
__global__ __launch_bounds__(256)
void stair_init(const float* __restrict__ h1, const float* __restrict__ h2,
                const float* __restrict__ h3, bf16* __restrict__ Hb,
                float* __restrict__ Hf) {
    int idx = blockIdx.x * 256 + threadIdx.x;   // < 3*32768
    int l = idx >> 15, r = idx & 32767;
    const float* src = (l == 0 ? h1 : (l == 1 ? h2 : h3));
    float v = src[r];
    Hb[l * 65536 + r] = __float2bfloat16(v);
    Hf[l * 32768 + r] = v;
}

// ---------------------------------------------------------------------------
// Staircase step s: layer l processes tl = s - l (if in range).
// Grid 192 = 3 layers x 64 unit-groups of 16. Block 256 (4 waves, K-split 4x256).
// Per block: gh = h_l[tl-1] @ Whh_l^T (MFMA), and for l>0 gi = c_{l-1}[tl] @ Wih_l^T.
// Swizzled-LDS k-reduce, then gates -> h_l[tl] (f32 in Hf, bf16 in Hb + C_l).
__global__ __launch_bounds__(256)
void staircase(int s, const float* __restrict__ GI0,
               const bf16* __restrict__ Wih2, const bf16* __restrict__ Wih3,
               const bf16* __restrict__ Whh1, const bf16* __restrict__ Whh2,
               const bf16* __restrict__ Whh3,
               const float* __restrict__ bih2, const float* __restrict__ bih3,
               const float* __restrict__ bhh1, const float* __restrict__ bhh2,
               const float* __restrict__ bhh3,
               bf16* __restrict__ c1, bf16* __restrict__ c2, bf16* __restrict__ c3,
               bf16* __restrict__ Hb, float* __restrict__ Hf) {
    const int l = blockIdx.x >> 6;
    const int tl = s - l;
    if (tl < 0 || tl >= T_) return;
    const int u0 = (blockIdx.x & 63) * 16;

    __shared__ float PlH[4 * 1536];   // 24KB
    __shared__ float PlI[4 * 1536];   // 24KB
    __shared__ float RrH[1536];       // 6KB
    __shared__ float RrI[1536];       // 6KB

    const bf16* Whh = (l == 0) ? Whh1 : ((l == 1) ? Whh2 : Whh3);
    const bf16* Wih = (l == 1) ? Wih2 : Wih3;
    const float* bhh = (l == 0) ? bhh1 : ((l == 1) ? bhh2 : bhh3);
    const float* bih = (l == 1) ? bih2 : bih3;
    const bf16* Aprev = (l == 1) ? c1 : c2;
    bf16* Cout = (l == 0) ? c1 : ((l == 1) ? c2 : c3);

    const int tid = threadIdx.x;
    const int lane = tid & 63;
    const int wid = tid >> 6;
    const int lr = lane & 15;
    const int lg = lane >> 4;
    const int kbase = wid * 256;

    const unsigned short* hsrc = (const unsigned short*)Hb + l * 65536 + (tl & 1) * 32768;
    const unsigned short* csrc = (const unsigned short*)Aprev + (size_t)tl * B_ * H_;
    const unsigned short* wh = (const unsigned short*)Whh;
    const unsigned short* wi = (const unsigned short*)Wih;

    f32x4 accH[2][3] = {};
    f32x4 accI[2][3] = {};
#pragma unroll
    for (int kf = 0; kf < 8; ++kf) {
        const int ko = kbase + kf * 32 + lg * 8;
        short8 a0 = *(const short8*)(hsrc + (size_t)lr * H_ + ko);
        short8 a1 = *(const short8*)(hsrc + (size_t)(16 + lr) * H_ + ko);
#pragma unroll
        for (int g = 0; g < 3; ++g) {
            short8 w = *(const short8*)(wh + (size_t)(g * H_ + u0 + lr) * H_ + ko);
            accH[0][g] = __builtin_amdgcn_mfma_f32_16x16x32_bf16(a0, w, accH[0][g], 0, 0, 0);
            accH[1][g] = __builtin_amdgcn_mfma_f32_16x16x32_bf16(a1, w, accH[1][g], 0, 0, 0);
        }
        if (l > 0) {
            short8 c0 = *(const short8*)(csrc + (size_t)lr * H_ + ko);
            short8 cv1 = *(const short8*)(csrc + (size_t)(16 + lr) * H_ + ko);
#pragma unroll
            for (int g = 0; g < 3; ++g) {
                short8 w = *(const short8*)(wi + (size_t)(g * H_ + u0 + lr) * H_ + ko);
                accI[0][g] = __builtin_amdgcn_mfma_f32_16x16x32_bf16(c0, w, accI[0][g], 0, 0, 0);
                accI[1][g] = __builtin_amdgcn_mfma_f32_16x16x32_bf16(cv1, w, accI[1][g], 0, 0, 0);
            }
        }
    }
    // psum -> LDS (swizzled): col = g*16+lr
#pragma unroll
    for (int m = 0; m < 2; ++m)
#pragma unroll
        for (int g = 0; g < 3; ++g) {
            int col = g * 16 + lr;
            int key = (col + (col >> 3)) & 7;
            int byte_off = wid * 6144 + col * 128 + (((m * 16 + lg * 4) * 4) ^ (key << 4));
            *(f32x4*)((char*)PlH + byte_off) = accH[m][g];
            if (l > 0) *(f32x4*)((char*)PlI + byte_off) = accI[m][g];
        }
    __syncthreads();
    // k-slice reduce + bias
#pragma unroll
    for (int it = 0; it < 2; ++it) {
        int task = tid + it * 256;
        if (task < 384) {
            int col = task >> 3, bq = task & 7;
            int key = (col + (col >> 3)) & 7;
            int boff = col * 128 + ((bq * 16) ^ (key << 4));
            float bh = bhh[(col >> 4) * H_ + u0 + (col & 15)];
            f32x4 s0 = *(const f32x4*)((const char*)PlH + boff);
            f32x4 s1 = *(const f32x4*)((const char*)PlH + 6144 + boff);
            f32x4 s2 = *(const f32x4*)((const char*)PlH + 12288 + boff);
            f32x4 s3 = *(const f32x4*)((const char*)PlH + 18432 + boff);
            f32x4 sv = (s0 + s1) + (s2 + s3);
            sv[0] += bh; sv[1] += bh; sv[2] += bh; sv[3] += bh;
            *(f32x4*)((char*)RrH + boff) = sv;
            if (l > 0) {
                float bi = bih[(col >> 4) * H_ + u0 + (col & 15)];
                f32x4 t0 = *(const f32x4*)((const char*)PlI + boff);
                f32x4 t1 = *(const f32x4*)((const char*)PlI + 6144 + boff);
                f32x4 t2 = *(const f32x4*)((const char*)PlI + 12288 + boff);
                f32x4 t3 = *(const f32x4*)((const char*)PlI + 18432 + boff);
                f32x4 tv = (t0 + t1) + (t2 + t3);
                tv[0] += bi; tv[1] += bi; tv[2] += bi; tv[3] += bi;
                *(f32x4*)((char*)RrI + boff) = tv;
            }
        }
    }
    __syncthreads();
    // gates
    unsigned short* hdst = (unsigned short*)Hb + l * 65536 + ((tl + 1) & 1) * 32768;
    float* hf = Hf + l * 32768;
#pragma unroll
    for (int it = 0; it < 2; ++it) {
        int p = tid + it * 256;
        int b = p >> 4, u = p & 15;
        int colR = u, colZ = 16 + u, colN = 32 + u;
        int keyR = (colR + (colR >> 3)) & 7;
        int keyZ = (colZ + (colZ >> 3)) & 7;
        int keyN = (colN + (colN >> 3)) & 7;
        float ghr = *(const float*)((const char*)RrH + colR * 128 + ((b * 4) ^ (keyR << 4)));
        float ghz = *(const float*)((const char*)RrH + colZ * 128 + ((b * 4) ^ (keyZ << 4)));
        float ghn = *(const float*)((const char*)RrH + colN * 128 + ((b * 4) ^ (keyN << 4)));
        float gir, giz, gin;
        if (l == 0) {
            const float* gi = GI0 + ((size_t)tl * B_ + b) * 3072 + u0 + u;
            gir = gi[0]; giz = gi[1024]; gin = gi[2048];
        } else {
            gir = *(const float*)((const char*)RrI + colR * 128 + ((b * 4) ^ (keyR << 4)));
            giz = *(const float*)((const char*)RrI + colZ * 128 + ((b * 4) ^ (keyZ << 4)));
            gin = *(const float*)((const char*)RrI + colN * 128 + ((b * 4) ^ (keyN << 4)));
        }
        float hold = hf[b * H_ + u0 + u];
        float rr = 1.f / (1.f + expf(-(gir + ghr)));
        float zz = 1.f / (1.f + expf(-(giz + ghz)));
        float nn = tanhf(gin + rr * ghn);
        float hnew = (1.f - zz) * nn + zz * hold;
        hf[b * H_ + u0 + u] = hnew;
        unsigned short hbv = __bfloat16_as_ushort(__float2bfloat16(hnew));
        hdst[(size_t)b * H_ + u0 + u] = hbv;
        ((unsigned short*)Cout)[((size_t)tl * B_ + b) * H_ + u0 + u] = hbv;
    }
}

// ---------------------------------------------------------------------------
// final h tails: out tail = Hf (f32), layer-major
__global__ __launch_bounds__(256)
void tail_kernel(const float* __restrict__ Hf, float* __restrict__ outt) {
    int idx = blockIdx.x * 256 + threadIdx.x;   // < 3*32768
    outt[idx] = Hf[idx];
}

// ---------------------------------------------------------------------------
extern "C" void kernel_launch(void* const* d_in, const int* in_sizes, int n_in,
                              void* d_out, int out_size, void* d_ws, size_t ws_size,
                              hipStream_t stream) {
    const int* tok = (const int*)d_in[0];
    const int* cat = (const int*)d_in[1];
    const float* h1 = (const float*)d_in[3];
    const float* h2 = (const float*)d_in[4];
    const float* h3 = (const float*)d_in[5];
    const float* wemb = (const float*)d_in[6];
    const float* cemb = (const float*)d_in[7];
    const float* Wih[3] = {(const float*)d_in[8], (const float*)d_in[12], (const float*)d_in[16]};
    const float* Whh[3] = {(const float*)d_in[9], (const float*)d_in[13], (const float*)d_in[17]};
    const float* bih[3] = {(const float*)d_in[10], (const float*)d_in[14], (const float*)d_in[18]};
    const float* bhh[3] = {(const float*)d_in[11], (const float*)d_in[15], (const float*)d_in[19]};
    const float* fcw = (const float*)d_in[20];
    const float* fcb = (const float*)d_in[21];
    float* out = (float*)d_out;

    // ws layout (bytes):
    //   C3    @ 0            8,388,608
    //   Xbf   @ 8,388,608   16,777,216 -> 25,165,824
    //   C1    @ 25,165,824   8,388,608 -> 33,554,432
    //   C2    @ 33,554,432   8,388,608 -> 41,943,040
    //   GI0   @ 41,943,040  50,331,648 -> 92,274,688
    //   fcwB  @ 8,388,608   65,536,000 -> 73,924,608  (reclaims Xbf/C1/C2/GI0 after staircase)
    //   WihB1 @ 92,274,688  12,582,912 -> 104,857,600 (only for GI0 GEMM)
    //   Hb    @ 92,274,688     393,216 -> 92,667,904  (overlays WihB1 after GI0 GEMM)
    //   Hf    @ 92,667,904     393,216 -> 93,061,120
    //   WihB2 @104,857,600   6,291,456 -> 111,149,056
    //   WihB3 @111,149,056   6,291,456 -> 117,440,512
    //   WhhB1 @117,440,512   6,291,456 -> 123,731,968
    //   WhhB2 @123,731,968   6,291,456 -> 130,023,424
    //   WhhB3 @130,023,424   6,291,456 -> 136,314,880
    char* ws = (char*)d_ws;
    bf16* C3 = (bf16*)ws;
    bf16* Xbf = (bf16*)(ws + 8388608);
    bf16* C1 = (bf16*)(ws + 25165824);
    bf16* C2 = (bf16*)(ws + 33554432);
    float* GI0 = (float*)(ws + 41943040);
    bf16* fcwB = (bf16*)(ws + 8388608);
    bf16* WihB1 = (bf16*)(ws + 92274688);
    bf16* Hb = (bf16*)(ws + 92274688);
    float* Hf = (float*)(ws + 92667904);
    bf16* WihB2 = (bf16*)(ws + 104857600);
    bf16* WihB3 = (bf16*)(ws + 111149056);
    bf16* WhhB1 = (bf16*)(ws + 117440512);
    bf16* WhhB2 = (bf16*)(ws + 123731968);
    bf16* WhhB3 = (bf16*)(ws + 130023424);

    conv_kernel<<<3072, 256, 0, stream>>>(Wih[0], WihB1, 786432);
    conv_kernel<<<1536, 256, 0, stream>>>(Wih[1], WihB2, 393216);
    conv_kernel<<<1536, 256, 0, stream>>>(Wih[2], WihB3, 393216);
    conv_kernel<<<1536, 256, 0, stream>>>(Whh[0], WhhB1, 393216);
    conv_kernel<<<1536, 256, 0, stream>>>(Whh[1], WhhB2, 393216);
    conv_kernel<<<1536, 256, 0, stream>>>(Whh[2], WhhB3, 393216);
    embed_kernel<<<T_ * B_, 256, 0, stream>>>(tok, cat, wemb, cemb, Xbf);

    // layer-1 gi, whole sequence (time-parallel)
    gemm_bt<0><<<dim3(32, 24), 256, 0, stream>>>(Xbf, WihB1, bih[0], GI0, 4096, 3072, 2048);

    // staircase recurrence (overlays WihB1 with Hb/Hf -- WihB1 dead after GI0 GEMM)
    stair_init<<<384, 256, 0, stream>>>(h1, h2, h3, Hb, Hf);
    for (int s = 0; s < T_ + 2; ++s) {
        staircase<<<192, 256, 0, stream>>>(s, GI0, WihB2, WihB3, WhhB1, WhhB2, WhhB3,
                                           bih[1], bih[2], bhh[0], bhh[1], bhh[2],
                                           C1, C2, C3, Hb, Hf);
    }

    conv_kernel<<<16000, 256, 0, stream>>>(fcw, fcwB, 4096000);
    gemm_bt<1><<<dim3(32, 250), 256, 0, stream>>>(C3, fcwB, fcb, out, 4096, 32000, 1024);
    tail_kernel<<<384, 256, 0, stream>>>(Hf, out + (size_t)B_ * T_ * V_);
}